// Round 1
// baseline (988.350 us; speedup 1.0000x reference)
//
#include <hip/hip_runtime.h>

// Problem constants
#define BB 16
#define NN 1024
#define FIN 64
#define FOUT 128
#define DD 64
#define HH 4
#define NEG 0.2f

#define RT 32    // rows per block
#define CTILE 128  // column tile in K2

// ---------------- Kernel 1: h_prime, attn_src, attn_dst, hp_sum ----------------
// grid: BB*(NN/RT) blocks, 256 threads
__global__ __launch_bounds__(256) void gat_k1(
    const float* __restrict__ h,      // [B,N,FIN]
    const float* __restrict__ w,      // [H,FIN,FOUT]
    const float* __restrict__ a_src,  // [H,FOUT,DD]
    const float* __restrict__ a_dst,  // [H,FOUT,DD]
    float* __restrict__ hp,           // [B,H,N,FOUT]
    float* __restrict__ asrc,         // [B,H,N,DD]
    float* __restrict__ adst,         // [B,H,N,DD]
    float* __restrict__ hpsum)        // [B,N,FOUT]
{
    __shared__ float hL[RT][FIN + 1];      // 32x65
    __shared__ float wL[FIN][FOUT + 2];    // 64x130
    __shared__ float hpL[RT][FOUT + 2];    // 32x130

    const int t  = threadIdx.x;
    const int tx = t & 31;
    const int ty = t >> 5;           // 0..7
    const int blk = blockIdx.x;
    const int b   = blk / (NN / RT);
    const int n0  = (blk % (NN / RT)) * RT;

    // load h tile (RT x FIN)
    for (int idx = t; idx < RT * FIN / 4; idx += 256) {
        int r = (idx * 4) / FIN;
        int f = (idx * 4) % FIN;
        float4 v = *reinterpret_cast<const float4*>(&h[((size_t)b * NN + n0 + r) * FIN + f]);
        hL[r][f + 0] = v.x; hL[r][f + 1] = v.y; hL[r][f + 2] = v.z; hL[r][f + 3] = v.w;
    }

    float sum_acc[4][4];
#pragma unroll
    for (int i = 0; i < 4; i++)
#pragma unroll
        for (int j = 0; j < 4; j++) sum_acc[i][j] = 0.f;

    for (int hh = 0; hh < HH; ++hh) {
        __syncthreads();  // protect wL/hpL from previous iteration readers
        // load w[hh] (FIN x FOUT)
        for (int idx = t; idx < FIN * FOUT / 4; idx += 256) {
            int k = (idx * 4) / FOUT;
            int o = (idx * 4) % FOUT;
            float4 v = *reinterpret_cast<const float4*>(&w[((size_t)hh * FIN + k) * FOUT + o]);
            wL[k][o + 0] = v.x; wL[k][o + 1] = v.y; wL[k][o + 2] = v.z; wL[k][o + 3] = v.w;
        }
        __syncthreads();

        // hp tile: rows i*8+ty, cols j*32+tx
        float acc[4][4];
#pragma unroll
        for (int i = 0; i < 4; i++)
#pragma unroll
            for (int j = 0; j < 4; j++) acc[i][j] = 0.f;

#pragma unroll 8
        for (int k = 0; k < FIN; k++) {
            float av0 = hL[ty][k], av1 = hL[ty + 8][k], av2 = hL[ty + 16][k], av3 = hL[ty + 24][k];
            float bv0 = wL[k][tx], bv1 = wL[k][tx + 32], bv2 = wL[k][tx + 64], bv3 = wL[k][tx + 96];
            acc[0][0] += av0 * bv0; acc[0][1] += av0 * bv1; acc[0][2] += av0 * bv2; acc[0][3] += av0 * bv3;
            acc[1][0] += av1 * bv0; acc[1][1] += av1 * bv1; acc[1][2] += av1 * bv2; acc[1][3] += av1 * bv3;
            acc[2][0] += av2 * bv0; acc[2][1] += av2 * bv1; acc[2][2] += av2 * bv2; acc[2][3] += av2 * bv3;
            acc[3][0] += av3 * bv0; acc[3][1] += av3 * bv1; acc[3][2] += av3 * bv2; acc[3][3] += av3 * bv3;
        }

        const size_t bh = (size_t)b * HH + hh;
#pragma unroll
        for (int i = 0; i < 4; i++) {
            int r = i * 8 + ty;
            size_t rowoff = (bh * NN + n0 + r) * FOUT;
#pragma unroll
            for (int j = 0; j < 4; j++) {
                int o = j * 32 + tx;
                hp[rowoff + o] = acc[i][j];
                hpL[r][o] = acc[i][j];
                sum_acc[i][j] += acc[i][j];
            }
        }
        __syncthreads();

        // attn_src / attn_dst: rows i*8+ty, d = tx and tx+32
        float as0[4], as1[4], ad0[4], ad1[4];
#pragma unroll
        for (int i = 0; i < 4; i++) { as0[i] = 0.f; as1[i] = 0.f; ad0[i] = 0.f; ad1[i] = 0.f; }

#pragma unroll 4
        for (int o = 0; o < FOUT; o++) {
            size_t aoff = ((size_t)hh * FOUT + o) * DD;
            float sv0 = a_src[aoff + tx];
            float sv1 = a_src[aoff + tx + 32];
            float dv0 = a_dst[aoff + tx];
            float dv1 = a_dst[aoff + tx + 32];
#pragma unroll
            for (int i = 0; i < 4; i++) {
                float hv = hpL[i * 8 + ty][o];
                as0[i] += hv * sv0; as1[i] += hv * sv1;
                ad0[i] += hv * dv0; ad1[i] += hv * dv1;
            }
        }
#pragma unroll
        for (int i = 0; i < 4; i++) {
            int r = i * 8 + ty;
            size_t base = (bh * NN + n0 + r) * DD;
            asrc[base + tx]      = as0[i];
            asrc[base + tx + 32] = as1[i];
            adst[base + tx]      = ad0[i];
            adst[base + tx + 32] = ad1[i];
        }
    }

    // hp_sum (over heads)
#pragma unroll
    for (int i = 0; i < 4; i++) {
        int r = i * 8 + ty;
        size_t rowoff = ((size_t)b * NN + n0 + r) * FOUT;
#pragma unroll
        for (int j = 0; j < 4; j++) {
            hpsum[rowoff + j * 32 + tx] = sum_acc[i][j];
        }
    }
}

// ---------------- Kernel 2: scores -> softmax -> attn out + PV + epilogue ----------------
// grid: BB*(NN/RT) blocks, 256 threads
__global__ __launch_bounds__(256) void gat_k2(
    const float* __restrict__ mask,   // [B,1,N,N]
    const float* __restrict__ bias,   // [FOUT]
    const float* __restrict__ hp,     // [B,H,N,FOUT]
    const float* __restrict__ asrc,   // [B,H,N,DD]
    const float* __restrict__ adst,   // [B,H,N,DD]
    const float* __restrict__ hpsum,  // [B,N,FOUT]
    float* __restrict__ out,          // [B,N,FOUT]
    float* __restrict__ attn)         // [B,H,N,N]
{
    __shared__ float asL[RT][DD + 1];        // 32x65
    __shared__ float adL[CTILE][DD + 1];     // 128x65
    __shared__ float pL[RT][CTILE + 2];      // 32x130
    __shared__ float hpcL[32][FOUT + 2];     // 32x130

    const int t  = threadIdx.x;
    const int tx = t & 31;
    const int ty = t >> 5;
    const int blk = blockIdx.x;
    const int b   = blk / (NN / RT);
    const int n0  = (blk % (NN / RT)) * RT;

    float oacc[4][4];
#pragma unroll
    for (int i = 0; i < 4; i++)
#pragma unroll
        for (int j = 0; j < 4; j++) oacc[i][j] = 0.f;

    for (int hh = 0; hh < HH; hh++) {
        const size_t bh = (size_t)b * HH + hh;

        __syncthreads();  // protect asL from previous head readers
        // load attn_src rows
        for (int idx = t; idx < RT * DD / 4; idx += 256) {
            int r = (idx * 4) / DD;
            int d = (idx * 4) % DD;
            float4 v = *reinterpret_cast<const float4*>(&asrc[(bh * NN + n0 + r) * DD + d]);
            asL[r][d + 0] = v.x; asL[r][d + 1] = v.y; asL[r][d + 2] = v.z; asL[r][d + 3] = v.w;
        }

        // ---- pass 1: row max + sum of exp(lrelu(s)) ----
        float m[4], l[4];
#pragma unroll
        for (int i = 0; i < 4; i++) { m[i] = -3.0e38f; l[i] = 0.f; }

        for (int ct = 0; ct < NN / CTILE; ct++) {
            __syncthreads();  // protect adL reuse
            for (int idx = t; idx < CTILE * DD / 4; idx += 256) {
                int c = (idx * 4) / DD;
                int d = (idx * 4) % DD;
                float4 v = *reinterpret_cast<const float4*>(&adst[(bh * NN + ct * CTILE + c) * DD + d]);
                adL[c][d + 0] = v.x; adL[c][d + 1] = v.y; adL[c][d + 2] = v.z; adL[c][d + 3] = v.w;
            }
            __syncthreads();

            float s[4][4];
#pragma unroll
            for (int i = 0; i < 4; i++)
#pragma unroll
                for (int j = 0; j < 4; j++) s[i][j] = 0.f;
#pragma unroll 8
            for (int k = 0; k < DD; k++) {
                float av0 = asL[ty][k], av1 = asL[ty + 8][k], av2 = asL[ty + 16][k], av3 = asL[ty + 24][k];
                float bv0 = adL[tx][k], bv1 = adL[tx + 32][k], bv2 = adL[tx + 64][k], bv3 = adL[tx + 96][k];
                s[0][0] += av0 * bv0; s[0][1] += av0 * bv1; s[0][2] += av0 * bv2; s[0][3] += av0 * bv3;
                s[1][0] += av1 * bv0; s[1][1] += av1 * bv1; s[1][2] += av1 * bv2; s[1][3] += av1 * bv3;
                s[2][0] += av2 * bv0; s[2][1] += av2 * bv1; s[2][2] += av2 * bv2; s[2][3] += av2 * bv3;
                s[3][0] += av3 * bv0; s[3][1] += av3 * bv1; s[3][2] += av3 * bv2; s[3][3] += av3 * bv3;
            }
#pragma unroll
            for (int i = 0; i < 4; i++) {
#pragma unroll
                for (int j = 0; j < 4; j++) {
                    float v = s[i][j];
                    s[i][j] = v > 0.f ? v : NEG * v;
                }
                float tm = fmaxf(fmaxf(s[i][0], s[i][1]), fmaxf(s[i][2], s[i][3]));
                float nm = fmaxf(m[i], tm);
                float sc = __expf(m[i] - nm);
                l[i] = l[i] * sc + __expf(s[i][0] - nm) + __expf(s[i][1] - nm)
                                 + __expf(s[i][2] - nm) + __expf(s[i][3] - nm);
                m[i] = nm;
            }
        }

        // butterfly reduce (m,l) across the 32 tx lanes (half-wave)
#pragma unroll
        for (int i = 0; i < 4; i++) {
#pragma unroll
            for (int off = 16; off >= 1; off >>= 1) {
                float om = __shfl_xor(m[i], off);
                float ol = __shfl_xor(l[i], off);
                float nm = fmaxf(m[i], om);
                l[i] = l[i] * __expf(m[i] - nm) + ol * __expf(om - nm);
                m[i] = nm;
            }
        }
        float rinv[4];
#pragma unroll
        for (int i = 0; i < 4; i++) rinv[i] = 1.0f / l[i];

        // ---- pass 2: attn write + PV accumulate ----
        for (int ct = 0; ct < NN / CTILE; ct++) {
            __syncthreads();  // protect adL/hpcL/pL reuse
            for (int idx = t; idx < CTILE * DD / 4; idx += 256) {
                int c = (idx * 4) / DD;
                int d = (idx * 4) % DD;
                float4 v = *reinterpret_cast<const float4*>(&adst[(bh * NN + ct * CTILE + c) * DD + d]);
                adL[c][d + 0] = v.x; adL[c][d + 1] = v.y; adL[c][d + 2] = v.z; adL[c][d + 3] = v.w;
            }
            __syncthreads();

            float s[4][4];
#pragma unroll
            for (int i = 0; i < 4; i++)
#pragma unroll
                for (int j = 0; j < 4; j++) s[i][j] = 0.f;
#pragma unroll 8
            for (int k = 0; k < DD; k++) {
                float av0 = asL[ty][k], av1 = asL[ty + 8][k], av2 = asL[ty + 16][k], av3 = asL[ty + 24][k];
                float bv0 = adL[tx][k], bv1 = adL[tx + 32][k], bv2 = adL[tx + 64][k], bv3 = adL[tx + 96][k];
                s[0][0] += av0 * bv0; s[0][1] += av0 * bv1; s[0][2] += av0 * bv2; s[0][3] += av0 * bv3;
                s[1][0] += av1 * bv0; s[1][1] += av1 * bv1; s[1][2] += av1 * bv2; s[1][3] += av1 * bv3;
                s[2][0] += av2 * bv0; s[2][1] += av2 * bv1; s[2][2] += av2 * bv2; s[2][3] += av2 * bv3;
                s[3][0] += av3 * bv0; s[3][1] += av3 * bv1; s[3][2] += av3 * bv2; s[3][3] += av3 * bv3;
            }

#pragma unroll
            for (int i = 0; i < 4; i++) {
                int r = i * 8 + ty;
                size_t mrow = ((size_t)b * NN + n0 + r) * NN + ct * CTILE;
                size_t arow = (bh * NN + n0 + r) * NN + ct * CTILE;
#pragma unroll
                for (int j = 0; j < 4; j++) {
                    int c = j * 32 + tx;
                    float v = s[i][j];
                    v = v > 0.f ? v : NEG * v;
                    float p = __expf(v - m[i]) * rinv[i];
                    p *= mask[mrow + c];
                    attn[arow + c] = p;
                    pL[r][c] = p;
                }
            }
            __syncthreads();  // pL ready

            // PV over this column tile, 4 chunks of 32
            for (int ch = 0; ch < 4; ch++) {
                if (ch) __syncthreads();  // protect hpcL
                for (int idx = t; idx < 32 * FOUT / 4; idx += 256) {
                    int cc = (idx * 4) / FOUT;
                    int o  = (idx * 4) % FOUT;
                    float4 v = *reinterpret_cast<const float4*>(
                        &hp[(bh * NN + ct * CTILE + ch * 32 + cc) * FOUT + o]);
                    hpcL[cc][o + 0] = v.x; hpcL[cc][o + 1] = v.y; hpcL[cc][o + 2] = v.z; hpcL[cc][o + 3] = v.w;
                }
                __syncthreads();
#pragma unroll 4
                for (int cc = 0; cc < 32; cc++) {
                    float pv0 = pL[ty][ch * 32 + cc], pv1 = pL[ty + 8][ch * 32 + cc];
                    float pv2 = pL[ty + 16][ch * 32 + cc], pv3 = pL[ty + 24][ch * 32 + cc];
                    float hv0 = hpcL[cc][tx], hv1 = hpcL[cc][tx + 32];
                    float hv2 = hpcL[cc][tx + 64], hv3 = hpcL[cc][tx + 96];
                    oacc[0][0] += pv0 * hv0; oacc[0][1] += pv0 * hv1; oacc[0][2] += pv0 * hv2; oacc[0][3] += pv0 * hv3;
                    oacc[1][0] += pv1 * hv0; oacc[1][1] += pv1 * hv1; oacc[1][2] += pv1 * hv2; oacc[1][3] += pv1 * hv3;
                    oacc[2][0] += pv2 * hv0; oacc[2][1] += pv2 * hv1; oacc[2][2] += pv2 * hv2; oacc[2][3] += pv2 * hv3;
                    oacc[3][0] += pv3 * hv0; oacc[3][1] += pv3 * hv1; oacc[3][2] += pv3 * hv2; oacc[3][3] += pv3 * hv3;
                }
            }
        }
    }

    // epilogue: + bias + skip (hp_sum)
#pragma unroll
    for (int i = 0; i < 4; i++) {
        int r = i * 8 + ty;
        size_t rowoff = ((size_t)b * NN + n0 + r) * FOUT;
#pragma unroll
        for (int j = 0; j < 4; j++) {
            int o = j * 32 + tx;
            out[rowoff + o] = oacc[i][j] + bias[o] + hpsum[rowoff + o];
        }
    }
}

extern "C" void kernel_launch(void* const* d_in, const int* in_sizes, int n_in,
                              void* d_out, int out_size, void* d_ws, size_t ws_size,
                              hipStream_t stream) {
    const float* h      = (const float*)d_in[0];
    const float* mask   = (const float*)d_in[1];
    const float* w      = (const float*)d_in[2];
    const float* a_src  = (const float*)d_in[3];
    const float* a_dst  = (const float*)d_in[4];
    const float* bias   = (const float*)d_in[5];

    float* out  = (float*)d_out;                          // [B,N,FOUT]
    float* attn = out + (size_t)BB * NN * FOUT;           // [B,H,N,N]

    // workspace layout (72 MB total)
    float* ws    = (float*)d_ws;
    float* hp    = ws;                                    // B*H*N*FOUT = 8M floats
    float* asrc  = hp   + (size_t)BB * HH * NN * FOUT;    // B*H*N*DD   = 4M
    float* adst  = asrc + (size_t)BB * HH * NN * DD;      // 4M
    float* hpsum = adst + (size_t)BB * HH * NN * DD;      // B*N*FOUT   = 2M

    dim3 grid(BB * (NN / RT));
    dim3 block(256);
    gat_k1<<<grid, block, 0, stream>>>(h, w, a_src, a_dst, hp, asrc, adst, hpsum);
    gat_k2<<<grid, block, 0, stream>>>(mask, bias, hp, asrc, adst, hpsum, out, attn);
}

// Round 2
// 316.768 us; speedup vs baseline: 3.1201x; 3.1201x over previous
//
#include <hip/hip_runtime.h>

// Problem constants
#define BB 16
#define NN 1024
#define FIN 64
#define FOUT 128
#define DD 64
#define HH 4
#define NEG 0.2f

#define RT 32     // rows per block
#define CT 128    // column tile in K2

typedef __attribute__((ext_vector_type(8))) short short8;
typedef __attribute__((ext_vector_type(4))) float f32x4;

__device__ __forceinline__ unsigned short f2bf(float x) {
    union { float f; unsigned u; } v; v.f = x;
    unsigned r = v.u + 0x7fffu + ((v.u >> 16) & 1u);
    return (unsigned short)(r >> 16);
}
__device__ __forceinline__ float bf2f(unsigned short s) {
    union { float f; unsigned u; } v; v.u = ((unsigned)s) << 16;
    return v.f;
}

#define MFMA(a, b, c) __builtin_amdgcn_mfma_f32_16x16x32_bf16((a), (b), (c), 0, 0, 0)

// ---------------- Kernel 1: h_prime (bf16 transposed), attn_src/dst (bf16 hi/lo), hp_sum ----------------
// grid: BB*(NN/RT) blocks, 256 threads
__global__ __launch_bounds__(256) void gat_k1(
    const float* __restrict__ h,      // [B,N,FIN]
    const float* __restrict__ w,      // [H,FIN,FOUT]
    const float* __restrict__ a_src,  // [H,FOUT,DD]
    const float* __restrict__ a_dst,  // [H,FOUT,DD]
    unsigned short* __restrict__ asHg,  // [B,H,N,DD] bf16 hi
    unsigned short* __restrict__ asLg,  // lo
    unsigned short* __restrict__ adHg,
    unsigned short* __restrict__ adLg,
    unsigned short* __restrict__ hpTg,  // [B,H,FOUT,N] bf16 (transposed h')
    float* __restrict__ hpsum)          // [B,N,FOUT]
{
    __shared__ float hL[RT][FIN + 1];      // 32x65
    __shared__ float wL[FIN][FOUT + 2];    // 64x130
    __shared__ float hpL[RT][FOUT + 2];    // 32x130

    const int t  = threadIdx.x;
    const int tx = t & 31;
    const int ty = t >> 5;           // 0..7
    const int blk = blockIdx.x;
    const int b   = blk / (NN / RT);
    const int n0  = (blk % (NN / RT)) * RT;

    // load h tile (RT x FIN)
    for (int idx = t; idx < RT * FIN / 4; idx += 256) {
        int r = (idx * 4) / FIN;
        int f = (idx * 4) % FIN;
        float4 v = *reinterpret_cast<const float4*>(&h[((size_t)b * NN + n0 + r) * FIN + f]);
        hL[r][f + 0] = v.x; hL[r][f + 1] = v.y; hL[r][f + 2] = v.z; hL[r][f + 3] = v.w;
    }

    float sum_acc[4][4];
#pragma unroll
    for (int i = 0; i < 4; i++)
#pragma unroll
        for (int j = 0; j < 4; j++) sum_acc[i][j] = 0.f;

    for (int hh = 0; hh < HH; ++hh) {
        __syncthreads();  // protect wL/hpL from previous iteration readers
        for (int idx = t; idx < FIN * FOUT / 4; idx += 256) {
            int k = (idx * 4) / FOUT;
            int o = (idx * 4) % FOUT;
            float4 v = *reinterpret_cast<const float4*>(&w[((size_t)hh * FIN + k) * FOUT + o]);
            wL[k][o + 0] = v.x; wL[k][o + 1] = v.y; wL[k][o + 2] = v.z; wL[k][o + 3] = v.w;
        }
        __syncthreads();

        float acc[4][4];
#pragma unroll
        for (int i = 0; i < 4; i++)
#pragma unroll
            for (int j = 0; j < 4; j++) acc[i][j] = 0.f;

#pragma unroll 8
        for (int k = 0; k < FIN; k++) {
            float av0 = hL[ty][k], av1 = hL[ty + 8][k], av2 = hL[ty + 16][k], av3 = hL[ty + 24][k];
            float bv0 = wL[k][tx], bv1 = wL[k][tx + 32], bv2 = wL[k][tx + 64], bv3 = wL[k][tx + 96];
            acc[0][0] += av0 * bv0; acc[0][1] += av0 * bv1; acc[0][2] += av0 * bv2; acc[0][3] += av0 * bv3;
            acc[1][0] += av1 * bv0; acc[1][1] += av1 * bv1; acc[1][2] += av1 * bv2; acc[1][3] += av1 * bv3;
            acc[2][0] += av2 * bv0; acc[2][1] += av2 * bv1; acc[2][2] += av2 * bv2; acc[2][3] += av2 * bv3;
            acc[3][0] += av3 * bv0; acc[3][1] += av3 * bv1; acc[3][2] += av3 * bv2; acc[3][3] += av3 * bv3;
        }

        const size_t bh = (size_t)b * HH + hh;
#pragma unroll
        for (int i = 0; i < 4; i++) {
            int r = i * 8 + ty;
#pragma unroll
            for (int j = 0; j < 4; j++) {
                int o = j * 32 + tx;
                hpL[r][o] = acc[i][j];
                sum_acc[i][j] += acc[i][j];
            }
        }
        __syncthreads();

        // attn_src / attn_dst
        float as0[4], as1[4], ad0[4], ad1[4];
#pragma unroll
        for (int i = 0; i < 4; i++) { as0[i] = 0.f; as1[i] = 0.f; ad0[i] = 0.f; ad1[i] = 0.f; }

#pragma unroll 4
        for (int o = 0; o < FOUT; o++) {
            size_t aoff = ((size_t)hh * FOUT + o) * DD;
            float sv0 = a_src[aoff + tx];
            float sv1 = a_src[aoff + tx + 32];
            float dv0 = a_dst[aoff + tx];
            float dv1 = a_dst[aoff + tx + 32];
#pragma unroll
            for (int i = 0; i < 4; i++) {
                float hv = hpL[i * 8 + ty][o];
                as0[i] += hv * sv0; as1[i] += hv * sv1;
                ad0[i] += hv * dv0; ad1[i] += hv * dv1;
            }
        }
#pragma unroll
        for (int i = 0; i < 4; i++) {
            int r = i * 8 + ty;
            size_t base = (bh * NN + n0 + r) * DD;
            unsigned short h0, h1;
            h0 = f2bf(as0[i]); asHg[base + tx]      = h0; asLg[base + tx]      = f2bf(as0[i] - bf2f(h0));
            h1 = f2bf(as1[i]); asHg[base + tx + 32] = h1; asLg[base + tx + 32] = f2bf(as1[i] - bf2f(h1));
            h0 = f2bf(ad0[i]); adHg[base + tx]      = h0; adLg[base + tx]      = f2bf(ad0[i] - bf2f(h0));
            h1 = f2bf(ad1[i]); adHg[base + tx + 32] = h1; adLg[base + tx + 32] = f2bf(ad1[i] - bf2f(h1));
        }

        // transposed bf16 h' : hpT[bh][o][n]
        {
            int o = t & 127, half = t >> 7;
            size_t dst = (bh * FOUT + o) * NN + n0 + half * 16;
            short8 v0, v1;
#pragma unroll
            for (int k = 0; k < 8; k++) v0[k] = (short)f2bf(hpL[half * 16 + k][o]);
#pragma unroll
            for (int k = 0; k < 8; k++) v1[k] = (short)f2bf(hpL[half * 16 + 8 + k][o]);
            *reinterpret_cast<short8*>(&hpTg[dst])     = v0;
            *reinterpret_cast<short8*>(&hpTg[dst + 8]) = v1;
        }
    }

    // hp_sum (over heads)
#pragma unroll
    for (int i = 0; i < 4; i++) {
        int r = i * 8 + ty;
        size_t rowoff = ((size_t)b * NN + n0 + r) * FOUT;
#pragma unroll
        for (int j = 0; j < 4; j++) {
            hpsum[rowoff + j * 32 + tx] = sum_acc[i][j];
        }
    }
}

// ---------------- Kernel 2: MFMA scores -> softmax -> attn + PV + epilogue ----------------
// grid: BB*(NN/RT) blocks, 256 threads (4 waves)
__global__ __launch_bounds__(256) void gat_k2(
    const float* __restrict__ mask,   // [B,1,N,N]
    const float* __restrict__ bias,   // [FOUT]
    const unsigned short* __restrict__ asHg,
    const unsigned short* __restrict__ asLg,
    const unsigned short* __restrict__ adHg,
    const unsigned short* __restrict__ adLg,
    const unsigned short* __restrict__ hpTg,  // [B,H,FOUT,N]
    const float* __restrict__ hpsum,  // [B,N,FOUT]
    float* __restrict__ out,          // [B,N,FOUT]
    float* __restrict__ attn)         // [B,H,N,N]
{
    // XOR-swizzled LDS tiles (T2): elem = row*stride + (k ^ ((row&maskbits)*8))
    __shared__ __align__(16) unsigned short adHs[CT * 64];    // 16 KB
    __shared__ __align__(16) unsigned short adLs[CT * 64];    // 16 KB
    __shared__ __align__(16) unsigned short asHs[RT * 64];    // 4 KB
    __shared__ __align__(16) unsigned short asLs[RT * 64];    // 4 KB
    __shared__ __align__(16) unsigned short pBs[RT * 128];    // 8 KB
    __shared__ __align__(16) unsigned short hpTs[128 * 64];   // 16 KB (reused as f32 out tile)
    __shared__ float2 red[4][32];                             // 1 KB

    const int t  = threadIdx.x;
    const int l  = t & 63;
    const int w  = t >> 6;
    const int li = l & 15;
    const int g  = l >> 4;
    const int b  = blockIdx.x / (NN / RT);
    const int n0 = (blockIdx.x % (NN / RT)) * RT;

    f32x4 oacc[2][2];
#pragma unroll
    for (int rf = 0; rf < 2; rf++)
#pragma unroll
        for (int of = 0; of < 2; of++) oacc[rf][of] = f32x4{0.f, 0.f, 0.f, 0.f};

    for (int hh = 0; hh < HH; hh++) {
        const size_t bh = (size_t)b * HH + hh;
        __syncthreads();
        // stage attn_src rows (32x64, hi+lo)
        {
            int r = t >> 3, j = t & 7;
            size_t src = (bh * NN + n0 + r) * DD + j * 8;
            int dst = r * 64 + ((j ^ (r & 7)) * 8);
            *reinterpret_cast<short8*>(&asHs[dst]) = *reinterpret_cast<const short8*>(&asHg[src]);
            *reinterpret_cast<short8*>(&asLs[dst]) = *reinterpret_cast<const short8*>(&asLg[src]);
        }
        __syncthreads();

        // preload A fragments (rows rf*16+li, k = ks*32 + g*8 .. +8)
        short8 aH[2][2], aL[2][2];
#pragma unroll
        for (int rf = 0; rf < 2; rf++)
#pragma unroll
            for (int ks = 0; ks < 2; ks++) {
                int r = rf * 16 + li;
                int off = r * 64 + ((ks * 32 + g * 8) ^ ((r & 7) * 8));
                aH[rf][ks] = *reinterpret_cast<const short8*>(&asHs[off]);
                aL[rf][ks] = *reinterpret_cast<const short8*>(&asLs[off]);
            }

        float mreg[2][4], lreg[2][4];
#pragma unroll
        for (int rf = 0; rf < 2; rf++)
#pragma unroll
            for (int q = 0; q < 4; q++) { mreg[rf][q] = -3.0e38f; lreg[rf][q] = 0.f; }

        // ================= pass 1: online (m,l) =================
        for (int ct = 0; ct < NN / CT; ct++) {
            __syncthreads();
#pragma unroll
            for (int i = 0; i < 4; i++) {
                int q = t + i * 256;
                int r = q >> 3, j = q & 7;
                size_t src = (bh * NN + (size_t)ct * CT + r) * DD + j * 8;
                int dst = r * 64 + ((j ^ (r & 7)) * 8);
                *reinterpret_cast<short8*>(&adHs[dst]) = *reinterpret_cast<const short8*>(&adHg[src]);
                *reinterpret_cast<short8*>(&adLs[dst]) = *reinterpret_cast<const short8*>(&adLg[src]);
            }
            __syncthreads();

            short8 bH[2][2], bL[2][2];
#pragma unroll
            for (int cf = 0; cf < 2; cf++)
#pragma unroll
                for (int ks = 0; ks < 2; ks++) {
                    int c = w * 32 + cf * 16 + li;
                    int off = c * 64 + ((ks * 32 + g * 8) ^ ((c & 7) * 8));
                    bH[cf][ks] = *reinterpret_cast<const short8*>(&adHs[off]);
                    bL[cf][ks] = *reinterpret_cast<const short8*>(&adLs[off]);
                }
            f32x4 sacc[2][2];
#pragma unroll
            for (int rf = 0; rf < 2; rf++)
#pragma unroll
                for (int cf = 0; cf < 2; cf++) sacc[rf][cf] = f32x4{0.f, 0.f, 0.f, 0.f};
#pragma unroll
            for (int ks = 0; ks < 2; ks++)
#pragma unroll
                for (int rf = 0; rf < 2; rf++)
#pragma unroll
                    for (int cf = 0; cf < 2; cf++) {
                        sacc[rf][cf] = MFMA(aH[rf][ks], bH[cf][ks], sacc[rf][cf]);
                        sacc[rf][cf] = MFMA(aH[rf][ks], bL[cf][ks], sacc[rf][cf]);
                        sacc[rf][cf] = MFMA(aL[rf][ks], bH[cf][ks], sacc[rf][cf]);
                    }
#pragma unroll
            for (int rf = 0; rf < 2; rf++)
#pragma unroll
                for (int q = 0; q < 4; q++) {
                    float v0 = sacc[rf][0][q]; v0 = v0 > 0.f ? v0 : NEG * v0;
                    float v1 = sacc[rf][1][q]; v1 = v1 > 0.f ? v1 : NEG * v1;
                    float nm = fmaxf(mreg[rf][q], fmaxf(v0, v1));
                    lreg[rf][q] = lreg[rf][q] * __expf(mreg[rf][q] - nm)
                                + __expf(v0 - nm) + __expf(v1 - nm);
                    mreg[rf][q] = nm;
                }
        }

        // butterfly within 16-lane groups (cols), then cross-wave via LDS
#pragma unroll
        for (int rf = 0; rf < 2; rf++)
#pragma unroll
            for (int q = 0; q < 4; q++) {
                float m = mreg[rf][q], lv = lreg[rf][q];
#pragma unroll
                for (int msk = 1; msk < 16; msk <<= 1) {
                    float om = __shfl_xor(m, msk);
                    float ol = __shfl_xor(lv, msk);
                    float nm = fmaxf(m, om);
                    lv = lv * __expf(m - nm) + ol * __expf(om - nm);
                    m = nm;
                }
                mreg[rf][q] = m; lreg[rf][q] = lv;
            }
        if (li == 0) {
#pragma unroll
            for (int rf = 0; rf < 2; rf++)
#pragma unroll
                for (int q = 0; q < 4; q++)
                    red[w][rf * 16 + g * 4 + q] = make_float2(mreg[rf][q], lreg[rf][q]);
        }
        __syncthreads();
        float mf[2][4], linv[2][4];
#pragma unroll
        for (int rf = 0; rf < 2; rf++)
#pragma unroll
            for (int q = 0; q < 4; q++) {
                int row = rf * 16 + g * 4 + q;
                float2 r0 = red[0][row], r1 = red[1][row], r2 = red[2][row], r3 = red[3][row];
                float m = fmaxf(fmaxf(r0.x, r1.x), fmaxf(r2.x, r3.x));
                float lv = r0.y * __expf(r0.x - m) + r1.y * __expf(r1.x - m)
                         + r2.y * __expf(r2.x - m) + r3.y * __expf(r3.x - m);
                mf[rf][q] = m;
                linv[rf][q] = 1.0f / lv;
            }

        // ================= pass 2: attn + PV =================
        for (int ct = 0; ct < NN / CT; ct++) {
            __syncthreads();
#pragma unroll
            for (int i = 0; i < 4; i++) {
                int q = t + i * 256;
                int r = q >> 3, j = q & 7;
                size_t src = (bh * NN + (size_t)ct * CT + r) * DD + j * 8;
                int dst = r * 64 + ((j ^ (r & 7)) * 8);
                *reinterpret_cast<short8*>(&adHs[dst]) = *reinterpret_cast<const short8*>(&adHg[src]);
                *reinterpret_cast<short8*>(&adLs[dst]) = *reinterpret_cast<const short8*>(&adLg[src]);
            }
            __syncthreads();

            short8 bH[2][2], bL[2][2];
#pragma unroll
            for (int cf = 0; cf < 2; cf++)
#pragma unroll
                for (int ks = 0; ks < 2; ks++) {
                    int c = w * 32 + cf * 16 + li;
                    int off = c * 64 + ((ks * 32 + g * 8) ^ ((c & 7) * 8));
                    bH[cf][ks] = *reinterpret_cast<const short8*>(&adHs[off]);
                    bL[cf][ks] = *reinterpret_cast<const short8*>(&adLs[off]);
                }
            f32x4 sacc[2][2];
#pragma unroll
            for (int rf = 0; rf < 2; rf++)
#pragma unroll
                for (int cf = 0; cf < 2; cf++) sacc[rf][cf] = f32x4{0.f, 0.f, 0.f, 0.f};
#pragma unroll
            for (int ks = 0; ks < 2; ks++)
#pragma unroll
                for (int rf = 0; rf < 2; rf++)
#pragma unroll
                    for (int cf = 0; cf < 2; cf++) {
                        sacc[rf][cf] = MFMA(aH[rf][ks], bH[cf][ks], sacc[rf][cf]);
                        sacc[rf][cf] = MFMA(aH[rf][ks], bL[cf][ks], sacc[rf][cf]);
                        sacc[rf][cf] = MFMA(aL[rf][ks], bH[cf][ks], sacc[rf][cf]);
                    }
            // normalized p -> pB (bf16, swizzled)
#pragma unroll
            for (int rf = 0; rf < 2; rf++)
#pragma unroll
                for (int cf = 0; cf < 2; cf++)
#pragma unroll
                    for (int q = 0; q < 4; q++) {
                        float v = sacc[rf][cf][q];
                        v = v > 0.f ? v : NEG * v;
                        float p = __expf(v - mf[rf][q]) * linv[rf][q];
                        int row = rf * 16 + g * 4 + q;
                        int c = w * 32 + cf * 16 + li;
                        pBs[row * 128 + (c ^ ((row & 15) * 8))] = f2bf(p);
                    }
            __syncthreads();
            // cooperative: attn = p*mask (coalesced), write masked p back to pB
            {
                int row = t >> 3, cb = (t & 7) * 16;
                int o0 = row * 128 + ((cb)     ^ ((row & 15) * 8));
                int o1 = row * 128 + ((cb + 8) ^ ((row & 15) * 8));
                short8 p0 = *reinterpret_cast<short8*>(&pBs[o0]);
                short8 p1 = *reinterpret_cast<short8*>(&pBs[o1]);
                const float* mp = mask + ((size_t)b * NN + n0 + row) * NN + (size_t)ct * CT + cb;
                float* ap = attn + (bh * NN + n0 + row) * NN + (size_t)ct * CT + cb;
                float pv[16];
#pragma unroll
                for (int k = 0; k < 8; k++) pv[k]     = bf2f((unsigned short)p0[k]);
#pragma unroll
                for (int k = 0; k < 8; k++) pv[k + 8] = bf2f((unsigned short)p1[k]);
#pragma unroll
                for (int k4 = 0; k4 < 4; k4++) {
                    float4 mv = *reinterpret_cast<const float4*>(&mp[k4 * 4]);
                    float4 av;
                    av.x = pv[k4 * 4 + 0] * mv.x; av.y = pv[k4 * 4 + 1] * mv.y;
                    av.z = pv[k4 * 4 + 2] * mv.z; av.w = pv[k4 * 4 + 3] * mv.w;
                    *reinterpret_cast<float4*>(&ap[k4 * 4]) = av;
                    pv[k4 * 4 + 0] = av.x; pv[k4 * 4 + 1] = av.y;
                    pv[k4 * 4 + 2] = av.z; pv[k4 * 4 + 3] = av.w;
                }
                short8 q0, q1;
#pragma unroll
                for (int k = 0; k < 8; k++) { q0[k] = (short)f2bf(pv[k]); q1[k] = (short)f2bf(pv[k + 8]); }
                *reinterpret_cast<short8*>(&pBs[o0]) = q0;
                *reinterpret_cast<short8*>(&pBs[o1]) = q1;
            }
            // PV: out[r][o] += P[r][c] * hpT[o][c], two 64-col sub-steps
#pragma unroll
            for (int s = 0; s < 2; s++) {
                __syncthreads();
#pragma unroll
                for (int i = 0; i < 4; i++) {
                    int q = t + i * 256;
                    int o = q >> 3, j = q & 7;
                    size_t src = (bh * FOUT + o) * NN + (size_t)ct * CT + s * 64 + j * 8;
                    int dst = o * 64 + ((j ^ (o & 7)) * 8);
                    *reinterpret_cast<short8*>(&hpTs[dst]) = *reinterpret_cast<const short8*>(&hpTg[src]);
                }
                __syncthreads();
                short8 pa[2][2], hb[2][2];
#pragma unroll
                for (int rf = 0; rf < 2; rf++)
#pragma unroll
                    for (int kc = 0; kc < 2; kc++) {
                        int r = rf * 16 + li;
                        int k = s * 64 + kc * 32 + g * 8;
                        pa[rf][kc] = *reinterpret_cast<const short8*>(&pBs[r * 128 + (k ^ ((r & 15) * 8))]);
                    }
#pragma unroll
                for (int of = 0; of < 2; of++)
#pragma unroll
                    for (int kc = 0; kc < 2; kc++) {
                        int o = w * 32 + of * 16 + li;
                        int k = kc * 32 + g * 8;
                        hb[of][kc] = *reinterpret_cast<const short8*>(&hpTs[o * 64 + (k ^ ((o & 7) * 8))]);
                    }
#pragma unroll
                for (int kc = 0; kc < 2; kc++)
#pragma unroll
                    for (int rf = 0; rf < 2; rf++)
#pragma unroll
                        for (int of = 0; of < 2; of++)
                            oacc[rf][of] = MFMA(pa[rf][kc], hb[of][kc], oacc[rf][of]);
            }
        }
    }

    // epilogue: stage oacc -> LDS (reuse hpTs as f32 32x128), then coalesced out write
    __syncthreads();
    float* outL = reinterpret_cast<float*>(hpTs);
#pragma unroll
    for (int rf = 0; rf < 2; rf++)
#pragma unroll
        for (int of = 0; of < 2; of++)
#pragma unroll
            for (int q = 0; q < 4; q++) {
                int row = rf * 16 + g * 4 + q;
                int col = w * 32 + of * 16 + li;
                outL[row * 128 + col] = oacc[rf][of][q];
            }
    __syncthreads();
    {
        int row = t >> 3, cb = (t & 7) * 16;
        size_t obase = ((size_t)b * NN + n0 + row) * FOUT + cb;
#pragma unroll
        for (int k4 = 0; k4 < 4; k4++) {
            float4 v  = *reinterpret_cast<float4*>(&outL[row * 128 + cb + k4 * 4]);
            float4 bs = *reinterpret_cast<const float4*>(&bias[cb + k4 * 4]);
            float4 hs = *reinterpret_cast<const float4*>(&hpsum[obase + k4 * 4]);
            v.x += bs.x + hs.x; v.y += bs.y + hs.y; v.z += bs.z + hs.z; v.w += bs.w + hs.w;
            *reinterpret_cast<float4*>(&out[obase + k4 * 4]) = v;
        }
    }
}

extern "C" void kernel_launch(void* const* d_in, const int* in_sizes, int n_in,
                              void* d_out, int out_size, void* d_ws, size_t ws_size,
                              hipStream_t stream) {
    const float* h      = (const float*)d_in[0];
    const float* mask   = (const float*)d_in[1];
    const float* w      = (const float*)d_in[2];
    const float* a_src  = (const float*)d_in[3];
    const float* a_dst  = (const float*)d_in[4];
    const float* bias   = (const float*)d_in[5];

    float* out  = (float*)d_out;                          // [B,N,FOUT]
    float* attn = out + (size_t)BB * NN * FOUT;           // [B,H,N,N]

    // workspace layout (56 MB total)
    const size_t NASD = (size_t)BB * HH * NN * DD;        // 4M elems
    unsigned short* asHg = (unsigned short*)d_ws;
    unsigned short* asLg = asHg + NASD;
    unsigned short* adHg = asLg + NASD;
    unsigned short* adLg = adHg + NASD;
    unsigned short* hpTg = adLg + NASD;                   // B*H*FOUT*N = 8M elems
    float* hpsum = (float*)(hpTg + (size_t)BB * HH * FOUT * NN);

    dim3 grid(BB * (NN / RT));
    dim3 block(256);
    gat_k1<<<grid, block, 0, stream>>>(h, w, a_src, a_dst, asHg, asLg, adHg, adLg, hpTg, hpsum);
    gat_k2<<<grid, block, 0, stream>>>(mask, bias, asHg, asLg, adHg, adLg, hpTg, hpsum, out, attn);
}